// Round 12
// baseline (947.357 us; speedup 1.0000x reference)
//
#include <hip/hip_runtime.h>

typedef unsigned short bfraw;
typedef __attribute__((ext_vector_type(8))) short short8v;
typedef __attribute__((ext_vector_type(8))) unsigned short ushort8v;
typedef __attribute__((ext_vector_type(4))) float f32x4;

static __device__ __forceinline__ float bf2f(unsigned short u) {
    union { unsigned int i; float f; } c; c.i = ((unsigned int)u) << 16; return c.f;
}
static __device__ __forceinline__ unsigned short f2bf(float f) {
    union { float f; unsigned int i; } c; c.f = f;
    unsigned int r = c.i + 0x7fffu + ((c.i >> 16) & 1u);
    return (unsigned short)(r >> 16);
}
static __device__ __forceinline__ unsigned short brelu(unsigned short u) {
    return (u & 0x8000u) ? (unsigned short)0 : u;   // bf16 relu via sign bit (exact)
}
static __device__ __forceinline__ f32x4 mfma16(short8v a, short8v b, f32x4 c) {
    return __builtin_amdgcn_mfma_f32_16x16x32_bf16(a, b, c, 0, 0, 0);
}

// Pack W (fp32 [Krows][300], starting at row_off):
// Wp[((ks*20+ct)*64+l)*8+j] = W[ks*32+(l>>4)*8+j][ct*16+(l&15)]  (0 outside)
__global__ __launch_bounds__(64) void k_pack(const float* __restrict__ W, int Krows, int row_off,
                                             bfraw* __restrict__ out) {
    const int b = blockIdx.x;           // b = ks*20 + ct
    const int ks = b / 20, ct = b - ks * 20;
    const int l = threadIdx.x;
    const int n = ct * 16 + (l & 15);
    const int kb = ks * 32 + (l >> 4) * 8;
    short8v pk;
#pragma unroll
    for (int j = 0; j < 8; ++j) {
        int k = kb + j;
        float v = (k < Krows && n < 300) ? W[(row_off + k) * 300 + n] : 0.f;
        pk[j] = (short)f2bf(v);
    }
    *(short8v*)&out[(b * 64 + l) * 8] = pk;
}

// ---------------- inp = f_bonds @ W_i  (bf16 pre-relu, stride 304) -----------
__global__ __launch_bounds__(512, 4) void k_in(const float* __restrict__ fb,
                                               const bfraw* __restrict__ Wp,
                                               bfraw* __restrict__ inp) {
    __shared__ short A[64 * 40 * 8];   // 40960 B
    const int row0 = blockIdx.x * 64;
    const int tid = threadIdx.x;
    // zero the K-pad region: logical chunks 18,19 of every row
    if (tid < 128) {
        int r = tid >> 1, c = 18 + (tid & 1);
        short8v z = {0, 0, 0, 0, 0, 0, 0, 0};
        *(short8v*)&A[(r * 40 + (c ^ (r & 7))) * 8] = z;
    }
    __syncthreads();
    // linear float4 staging: block's 64 rows = 9408 consecutive floats (16B-aligned)
    const float4* fb4 = (const float4*)(fb + (long long)row0 * 147);
#pragma unroll 1
    for (int s = 0; s < 5; ++s) {
        int idx = tid + s * 512;
        if (idx < 2352) {
            float4 v = fb4[idx];
            const float* ve = (const float*)&v;
            int k0 = idx * 4;
#pragma unroll
            for (int e = 0; e < 4; ++e) {
                int k = k0 + e;
                int r = k / 147;
                int c = k - r * 147;
                A[(r * 40 + ((c >> 3) ^ (r & 7))) * 8 + (c & 7)] = (short)f2bf(ve[e]);
            }
        }
    }
    __syncthreads();
    const int w = tid >> 6, l = tid & 63;
    const int wr = w >> 2, wc = w & 3;
    const int lr = l & 15, lk = l >> 4, sw = l & 7;
    f32x4 acc[2][5];
#pragma unroll
    for (int ri = 0; ri < 2; ++ri)
#pragma unroll
        for (int i = 0; i < 5; ++i) acc[ri][i] = (f32x4){0.f, 0.f, 0.f, 0.f};
    const short8v* Ald = (const short8v*)A;
#pragma unroll
    for (int ks = 0; ks < 5; ++ks) {
        short8v bfr[2], wv[5];
#pragma unroll
        for (int ri = 0; ri < 2; ++ri)
            bfr[ri] = Ald[((wr * 2 + ri) * 16 + lr) * 40 + ((ks * 4 + lk) ^ sw)];
#pragma unroll
        for (int i = 0; i < 5; ++i)
            wv[i] = *(const short8v*)&Wp[((ks * 20 + wc * 5 + i) * 64 + l) * 8];
#pragma unroll
        for (int ri = 0; ri < 2; ++ri)
#pragma unroll
            for (int i = 0; i < 5; ++i)
                acc[ri][i] = mfma16(wv[i], bfr[ri], acc[ri][i]);
    }
    __syncthreads();
#pragma unroll
    for (int ri = 0; ri < 2; ++ri)
#pragma unroll
        for (int i = 0; i < 5; ++i) {
            const int r = (wr * 2 + ri) * 16 + lr;
            const int c16 = (wc * 5 + i) * 2 + (lk >> 1);
            ushort4 t;
            t.x = f2bf(acc[ri][i][0]); t.y = f2bf(acc[ri][i][1]);
            t.z = f2bf(acc[ri][i][2]); t.w = f2bf(acc[ri][i][3]);
            *(ushort4*)&A[(r * 40 + (c16 ^ (r & 7))) * 8 + (lk & 1) * 4] = t;
        }
    __syncthreads();
    for (int idx = tid; idx < 64 * 38; idx += 512) {
        int r = idx / 38, c = idx - r * 38;
        short8v t = *(const short8v*)&A[(r * 40 + (c ^ (r & 7))) * 8];
        *(short8v*)&inp[(long long)(row0 + r) * 304 + c * 8] = t;
    }
}

// ------ a_msg[a] = sum_nb brelu(msg[a2b[a][nb]])  (bf16, stride 304) ---------
__global__ __launch_bounds__(256) void k_gather(const bfraw* __restrict__ msg,
                                                const int* __restrict__ a2b,
                                                bfraw* __restrict__ amsg) {
    int gid = blockIdx.x * 256 + threadIdx.x;
    if (gid >= 100000 * 19) return;
    int a = gid / 19, c = gid - a * 19;      // handles chunks c and c+19
    const int* nb = a2b + a * 6;
    float s0[8], s1[8];
#pragma unroll
    for (int e = 0; e < 8; ++e) { s0[e] = 0.f; s1[e] = 0.f; }
#pragma unroll
    for (int j = 0; j < 6; ++j) {
        const long long base = (long long)nb[j] * 304;
        const ushort8v v0 = *(const ushort8v*)&msg[base + c * 8];
        const ushort8v v1 = *(const ushort8v*)&msg[base + (c + 19) * 8];
#pragma unroll
        for (int e = 0; e < 8; ++e) {
            s0[e] += bf2f(brelu(v0[e]));
            s1[e] += bf2f(brelu(v1[e]));
        }
    }
    short8v o0, o1;
#pragma unroll
    for (int e = 0; e < 8; ++e) { o0[e] = (short)f2bf(s0[e]); o1[e] = (short)f2bf(s1[e]); }
    *(short8v*)&amsg[(long long)a * 304 + c * 8] = o0;
    *(short8v*)&amsg[(long long)a * 304 + (c + 19) * 8] = o1;
}

// --- out = inp + (amsg[b2a] - brelu(msg[b2revb])) @ W_h  (bf16 pre-relu) -----
// BARRIER-FREE: each wave owns 16 bond rows end-to-end in a private LDS slice.
// Block = 8 waves x 16 rows = 128 rows; LDS 80KB -> 2 blocks/CU.
__global__ __launch_bounds__(512, 4) void k_bond(const bfraw* __restrict__ amsg,
                                                 const bfraw* __restrict__ msg,
                                                 const bfraw* __restrict__ inp,
                                                 const int* __restrict__ b2a,
                                                 const int* __restrict__ b2revb,
                                                 const bfraw* __restrict__ Wp,
                                                 bfraw* __restrict__ out) {
    __shared__ short A[128 * 40 * 8];   // 81920 B
    const int tid = threadIdx.x;
    const int w = tid >> 6, l = tid & 63;
    const int wrow0 = blockIdx.x * 128 + w * 16;   // wave's first bond row
    short* Aw = A + w * 16 * 40 * 8;               // wave's private 16-row slice
    const int lr = l & 15, lk = l >> 4, sw = l & 7;
    // zero K-pad chunks 38,39 of own rows (32 units, lanes 0..31)
    if (l < 32) {
        int r = l >> 1, c = 38 + (l & 1);
        short8v z = {0, 0, 0, 0, 0, 0, 0, 0};
        *(short8v*)&Aw[(r * 40 + (c ^ (r & 7))) * 8] = z;
    }
    // staging: 16 rows x 38 chunks = 608 units, 10 per lane, 2 groups of 5
    // (10 scattered 16B loads in flight per lane per group)
#pragma unroll
    for (int g = 0; g < 2; ++g) {
        int rr[5], cc[5];
        ushort8v va[5], vm[5];
#pragma unroll
        for (int u = 0; u < 5; ++u) {
            int idx = l + (g * 5 + u) * 64;
            rr[u] = idx / 38; cc[u] = idx - rr[u] * 38;
            int b = wrow0 + rr[u];
            int ok = (idx < 608) && (b < 200000);
            int ia  = ok ? b2a[b] : 0;
            int irv = ok ? b2revb[b] : 0;
            va[u] = *(const ushort8v*)&amsg[(long long)ia * 304 + cc[u] * 8];
            vm[u] = *(const ushort8v*)&msg[(long long)irv * 304 + cc[u] * 8];
        }
#pragma unroll
        for (int u = 0; u < 5; ++u) {
            int idx = l + (g * 5 + u) * 64;
            if (idx < 608) {
                short8v pk;
#pragma unroll
                for (int j = 0; j < 8; ++j)
                    pk[j] = (short)f2bf(bf2f(va[u][j]) - bf2f(brelu(vm[u][j])));
                *(short8v*)&Aw[(rr[u] * 40 + (cc[u] ^ (rr[u] & 7))) * 8] = pk;
            }
        }
    }
    // MFMA: wave reads only its own slice (wave-synchronous; no barrier).
    f32x4 acc[20];
#pragma unroll
    for (int i = 0; i < 20; ++i) acc[i] = (f32x4){0.f, 0.f, 0.f, 0.f};
    const short8v* Awl = (const short8v*)Aw;
#pragma unroll
    for (int ks = 0; ks < 10; ++ks) {
        short8v af = Awl[lr * 40 + ((ks * 4 + lk) ^ sw)];
#pragma unroll
        for (int i0 = 0; i0 < 20; i0 += 5) {
            short8v wv[5];
#pragma unroll
            for (int i = 0; i < 5; ++i)
                wv[i] = *(const short8v*)&Wp[((ks * 20 + i0 + i) * 64 + l) * 8];
#pragma unroll
            for (int i = 0; i < 5; ++i)
                acc[i0 + i] = mfma16(wv[i], af, acc[i0 + i]);
        }
    }
    // bounce own acc into own slice (in-wave LDS ordering suffices)
#pragma unroll
    for (int i = 0; i < 20; ++i) {
        const int c16 = i * 2 + (lk >> 1);
        ushort4 t;
        t.x = f2bf(acc[i][0]); t.y = f2bf(acc[i][1]);
        t.z = f2bf(acc[i][2]); t.w = f2bf(acc[i][3]);
        *(ushort4*)&Aw[(lr * 40 + (c16 ^ (lr & 7))) * 8 + (lk & 1) * 4] = t;
    }
    // epilogue: coalesced readback + inp add + store (own 16 rows)
#pragma unroll
    for (int u = 0; u < 10; ++u) {
        int idx = l + u * 64;
        if (idx < 608) {
            int r = idx / 38, c = idx - r * 38;
            const long long row = wrow0 + r;
            if (row < 200000) {
                short8v t = *(const short8v*)&Aw[(r * 40 + (c ^ (r & 7))) * 8];
                const ushort8v ip = *(const ushort8v*)&inp[row * 304 + c * 8];
                short8v m;
#pragma unroll
                for (int j = 0; j < 8; ++j)
                    m[j] = (short)f2bf(bf2f(ip[j]) + bf2f((unsigned short)t[j]));
                *(short8v*)&out[row * 304 + c * 8] = m;
            }
        }
    }
}

// --- hid = relu(f_atoms @ Wo_fa + (gather msg) @ Wo_am + b_o) (bf16) ---------
// Gather #3 fused into phase-1 staging (pair-batched: 12 loads in flight).
__global__ __launch_bounds__(512, 4) void k_out(const float* __restrict__ fa,
                                                const bfraw* __restrict__ msg,
                                                const int* __restrict__ a2b,
                                                const bfraw* __restrict__ WfP,
                                                const bfraw* __restrict__ WaP,
                                                const float* __restrict__ bo,
                                                bfraw* __restrict__ hid) {
    __shared__ short A[64 * 40 * 8];
    const int row0 = blockIdx.x * 64;
    const int tid = threadIdx.x;
    const int nvalid = (row0 + 64 <= 100000) ? 64 : (100000 - row0);
    // phase 1 staging: amsg row = sum_j brelu(msg[a2b[row][j]]); 2-unit batches
#pragma unroll 1
    for (int sp = 0; sp < 5; sp += 2) {
        ushort8v v[2][6];
        int ur[2], uc[2], act[2];
#pragma unroll
        for (int u = 0; u < 2; ++u) {
            act[u] = 0;
            int s = sp + u;
            if (s < 5) {
                int idx = tid + s * 512;
                int r = idx / 40, c = idx - r * 40;
                ur[u] = r; uc[u] = c;
                const int row = row0 + r;
                if (c < 38 && row < 100000) {
                    act[u] = 1;
                    const int* nb = a2b + row * 6;
#pragma unroll
                    for (int j = 0; j < 6; ++j)
                        v[u][j] = *(const ushort8v*)&msg[(long long)nb[j] * 304 + c * 8];
                }
            }
        }
#pragma unroll
        for (int u = 0; u < 2; ++u) {
            int s = sp + u;
            if (s >= 5) continue;
            short8v pk;
            if (act[u]) {
                float sm[8];
#pragma unroll
                for (int e = 0; e < 8; ++e) sm[e] = 0.f;
#pragma unroll
                for (int j = 0; j < 6; ++j)
#pragma unroll
                    for (int e = 0; e < 8; ++e) sm[e] += bf2f(brelu(v[u][j][e]));
#pragma unroll
                for (int e = 0; e < 8; ++e) pk[e] = (short)f2bf(sm[e]);
            } else {
#pragma unroll
                for (int e = 0; e < 8; ++e) pk[e] = 0;
            }
            *(short8v*)&A[(ur[u] * 40 + (uc[u] ^ (ur[u] & 7))) * 8] = pk;
        }
    }
    __syncthreads();
    const int w = tid >> 6, l = tid & 63;
    const int wr = w >> 2, wc = w & 3;
    const int lr = l & 15, lk = l >> 4, sw = l & 7;
    f32x4 acc[2][5];
#pragma unroll
    for (int ri = 0; ri < 2; ++ri)
#pragma unroll
        for (int i = 0; i < 5; ++i) acc[ri][i] = (f32x4){0.f, 0.f, 0.f, 0.f};
    const short8v* Ald = (const short8v*)A;
#pragma unroll
    for (int ks = 0; ks < 10; ++ks) {
        short8v bfr[2], wv[5];
#pragma unroll
        for (int ri = 0; ri < 2; ++ri)
            bfr[ri] = Ald[((wr * 2 + ri) * 16 + lr) * 40 + ((ks * 4 + lk) ^ sw)];
#pragma unroll
        for (int i = 0; i < 5; ++i)
            wv[i] = *(const short8v*)&WaP[((ks * 20 + wc * 5 + i) * 64 + l) * 8];
#pragma unroll
        for (int ri = 0; ri < 2; ++ri)
#pragma unroll
            for (int i = 0; i < 5; ++i)
                acc[ri][i] = mfma16(wv[i], bfr[ri], acc[ri][i]);
    }
    __syncthreads();
    // phase 2: f_atoms @ Wo_fa (accumulate). Zero K-pad chunks 16..19 first.
    if (tid < 256) {
        int r = tid >> 2, c = 16 + (tid & 3);
        short8v z = {0, 0, 0, 0, 0, 0, 0, 0};
        *(short8v*)&A[(r * 40 + (c ^ (r & 7))) * 8] = z;
    }
    __syncthreads();
    // linear float4 staging of f_atoms
    {
        const float4* fa4 = (const float4*)(fa + (long long)row0 * 133);
        const int limit4 = (nvalid * 133) >> 2;
#pragma unroll 1
        for (int s = 0; s < 5; ++s) {
            int idx = tid + s * 512;
            if (idx < limit4) {
                float4 v = fa4[idx];
                const float* ve = (const float*)&v;
                int k0 = idx * 4;
#pragma unroll
                for (int e = 0; e < 4; ++e) {
                    int k = k0 + e;
                    int r = k / 133;
                    int c = k - r * 133;
                    A[(r * 40 + ((c >> 3) ^ (r & 7))) * 8 + (c & 7)] = (short)f2bf(ve[e]);
                }
            }
        }
    }
    __syncthreads();
#pragma unroll
    for (int ks = 0; ks < 5; ++ks) {
        short8v bfr[2], wv[5];
#pragma unroll
        for (int ri = 0; ri < 2; ++ri)
            bfr[ri] = Ald[((wr * 2 + ri) * 16 + lr) * 40 + ((ks * 4 + lk) ^ sw)];
#pragma unroll
        for (int i = 0; i < 5; ++i)
            wv[i] = *(const short8v*)&WfP[((ks * 20 + wc * 5 + i) * 64 + l) * 8];
#pragma unroll
        for (int ri = 0; ri < 2; ++ri)
#pragma unroll
            for (int i = 0; i < 5; ++i)
                acc[ri][i] = mfma16(wv[i], bfr[ri], acc[ri][i]);
    }
    __syncthreads();
#pragma unroll
    for (int ri = 0; ri < 2; ++ri)
#pragma unroll
        for (int i = 0; i < 5; ++i) {
            const int r = (wr * 2 + ri) * 16 + lr;
            const int c16 = (wc * 5 + i) * 2 + (lk >> 1);
            ushort4 t;
            t.x = f2bf(acc[ri][i][0]); t.y = f2bf(acc[ri][i][1]);
            t.z = f2bf(acc[ri][i][2]); t.w = f2bf(acc[ri][i][3]);
            *(ushort4*)&A[(r * 40 + (c16 ^ (r & 7))) * 8 + (lk & 1) * 4] = t;
        }
    __syncthreads();
    for (int idx = tid; idx < 64 * 38; idx += 512) {
        int r = idx / 38, c = idx - r * 38;
        const int row = row0 + r;
        if (row >= 100000) continue;
        short8v t = *(const short8v*)&A[(r * 40 + (c ^ (r & 7))) * 8];
        float4 b0 = *(const float4*)&bo[c * 8];
        float4 b1 = (c < 37) ? *(const float4*)&bo[c * 8 + 4]
                             : make_float4(0.f, 0.f, 0.f, 0.f);
        float bias[8] = {b0.x, b0.y, b0.z, b0.w, b1.x, b1.y, b1.z, b1.w};
        short8v m;
#pragma unroll
        for (int j = 0; j < 8; ++j)
            m[j] = (short)f2bf(fmaxf(bf2f((unsigned short)t[j]) + bias[j], 0.f));
        *(short8v*)&hid[(long long)row * 304 + c * 8] = m;
    }
}

// ------- out[m] = mean of hid rows with mol_ids == m (0 if none) -------------
__global__ __launch_bounds__(320) void k_mean(const bfraw* __restrict__ hid,
                                              const int* __restrict__ mol,
                                              float* __restrict__ out) {
    __shared__ float red[8][304];
    const int m = blockIdx.x;
    const int natoms = 100000;
    int lo = 0, hi = natoms;
    while (lo < hi) { int mid = (lo + hi) >> 1; if (mol[mid] < m) lo = mid + 1; else hi = mid; }
    const int start = lo;
    lo = start; hi = natoms;
    while (lo < hi) { int mid = (lo + hi) >> 1; if (mol[mid] <= m) lo = mid + 1; else hi = mid; }
    const int end = lo;
    const int tid = threadIdx.x;
    const int p = tid / 38, c = tid - p * 38;   // valid for tid < 304
    if (tid < 304) {
        float s[8];
#pragma unroll
        for (int e = 0; e < 8; ++e) s[e] = 0.f;
        for (int a = start + p; a < end; a += 8) {
            const ushort8v v = *(const ushort8v*)&hid[(long long)a * 304 + c * 8];
#pragma unroll
            for (int e = 0; e < 8; ++e) s[e] += bf2f(v[e]);
        }
#pragma unroll
        for (int e = 0; e < 8; ++e) red[p][c * 8 + e] = s[e];
    }
    __syncthreads();
    if (tid < 300) {
        float t = 0.f;
#pragma unroll
        for (int p2 = 0; p2 < 8; ++p2) t += red[p2][tid];
        const int n = end - start;
        out[m * 300 + tid] = (n > 0) ? (t / (float)n) : 0.f;
    }
}

extern "C" void kernel_launch(void* const* d_in, const int* in_sizes, int n_in,
                              void* d_out, int out_size, void* d_ws, size_t ws_size,
                              hipStream_t stream) {
    const float* f_atoms = (const float*)d_in[0];
    const float* f_bonds = (const float*)d_in[1];
    const int* a2b      = (const int*)d_in[2];
    const int* b2a      = (const int*)d_in[3];
    const int* b2revb   = (const int*)d_in[4];
    const int* mol_ids  = (const int*)d_in[5];
    const float* W_i    = (const float*)d_in[6];
    const float* W_h    = (const float*)d_in[7];
    const float* W_o    = (const float*)d_in[8];
    const float* b_o    = (const float*)d_in[9];
    float* out = (float*)d_out;

    // ws layout (bytes): bf16 rows at stride 304 (608 B); msgs PRE-relu
    //   inp  @ 0            121,600,000
    //   M1   @ 121,600,000  121,600,000  (bond1 out; reused as hid)
    //   M2   @ 243,200,000  121,600,000  (bond2 out)
    //   amsg @ 364,800,000   60,800,000
    //   packed weights @ 425,600,000
    char* wsb = (char*)d_ws;
    bfraw* inp  = (bfraw*)(wsb);
    bfraw* M1   = (bfraw*)(wsb + 121600000ll);
    bfraw* M2   = (bfraw*)(wsb + 243200000ll);
    bfraw* amsg = (bfraw*)(wsb + 364800000ll);
    bfraw* WiP   = (bfraw*)(wsb + 425600000ll);
    bfraw* WhP   = (bfraw*)(wsb + 425702400ll);
    bfraw* WoFaP = (bfraw*)(wsb + 425907200ll);
    bfraw* WoAmP = (bfraw*)(wsb + 426009600ll);

    k_pack<<<100, 64, 0, stream>>>(W_i, 147, 0, WiP);
    k_pack<<<200, 64, 0, stream>>>(W_h, 300, 0, WhP);
    k_pack<<<100, 64, 0, stream>>>(W_o, 133, 0, WoFaP);
    k_pack<<<200, 64, 0, stream>>>(W_o, 300, 133, WoAmP);

    const int nb_blocks = 200000 / 64;            // 3125 (k_in)
    const int nb2_blocks = (200000 + 127) / 128;  // 1563 (barrier-free k_bond)
    const int na_blocks = (100000 + 63) / 64;     // 1563
    const int gather_blocks = (100000 * 19 + 255) / 256;

    k_in<<<nb_blocks, 512, 0, stream>>>(f_bonds, WiP, inp);

    k_gather<<<gather_blocks, 256, 0, stream>>>(inp, a2b, amsg);
    k_bond<<<nb2_blocks, 512, 0, stream>>>(amsg, inp, inp, b2a, b2revb, WhP, M1);
    k_gather<<<gather_blocks, 256, 0, stream>>>(M1, a2b, amsg);
    k_bond<<<nb2_blocks, 512, 0, stream>>>(amsg, M1, inp, b2a, b2revb, WhP, M2);

    bfraw* hid = M1;   // M1 dead after bond2
    k_out<<<na_blocks, 512, 0, stream>>>(f_atoms, M2, a2b, WoFaP, WoAmP, b_o, hid);
    k_mean<<<4000, 320, 0, stream>>>(hid, mol_ids, out);
}

// Round 13
// 602.481 us; speedup vs baseline: 1.5724x; 1.5724x over previous
//
#include <hip/hip_runtime.h>

typedef unsigned short bfraw;
typedef __attribute__((ext_vector_type(8))) short short8v;
typedef __attribute__((ext_vector_type(8))) unsigned short ushort8v;
typedef __attribute__((ext_vector_type(4))) float f32x4;

static __device__ __forceinline__ float bf2f(unsigned short u) {
    union { unsigned int i; float f; } c; c.i = ((unsigned int)u) << 16; return c.f;
}
static __device__ __forceinline__ unsigned short f2bf(float f) {
    union { float f; unsigned int i; } c; c.f = f;
    unsigned int r = c.i + 0x7fffu + ((c.i >> 16) & 1u);
    return (unsigned short)(r >> 16);
}
static __device__ __forceinline__ unsigned short brelu(unsigned short u) {
    return (u & 0x8000u) ? (unsigned short)0 : u;   // bf16 relu via sign bit (exact)
}
static __device__ __forceinline__ f32x4 mfma16(short8v a, short8v b, f32x4 c) {
    return __builtin_amdgcn_mfma_f32_16x16x32_bf16(a, b, c, 0, 0, 0);
}

// Pack W (fp32 [Krows][300], starting at row_off):
// Wp[((ks*20+ct)*64+l)*8+j] = W[ks*32+(l>>4)*8+j][ct*16+(l&15)]  (0 outside)
__global__ __launch_bounds__(64) void k_pack(const float* __restrict__ W, int Krows, int row_off,
                                             bfraw* __restrict__ out) {
    const int b = blockIdx.x;           // b = ks*20 + ct
    const int ks = b / 20, ct = b - ks * 20;
    const int l = threadIdx.x;
    const int n = ct * 16 + (l & 15);
    const int kb = ks * 32 + (l >> 4) * 8;
    short8v pk;
#pragma unroll
    for (int j = 0; j < 8; ++j) {
        int k = kb + j;
        float v = (k < Krows && n < 300) ? W[(row_off + k) * 300 + n] : 0.f;
        pk[j] = (short)f2bf(v);
    }
    *(short8v*)&out[(b * 64 + l) * 8] = pk;
}

// Geometry: 64-row tile, 512 thr = 8 waves (2 row-groups x 4 col-groups),
// LDS stride 40 chunks (16B) XOR-swizzled; swapped MFMA (lane = 4 consecutive
// out-cols of one row); epilogue bounces acc through the same LDS buffer.
// Message buffers hold PRE-relu values; consumers apply brelu on load.

// ---------------- inp = f_bonds @ W_i  (bf16 pre-relu, stride 304) -----------
__global__ __launch_bounds__(512, 4) void k_in(const float* __restrict__ fb,
                                               const bfraw* __restrict__ Wp,
                                               bfraw* __restrict__ inp) {
    __shared__ short A[64 * 40 * 8];   // 40960 B
    const int row0 = blockIdx.x * 64;
    const int tid = threadIdx.x;
    // zero the K-pad region: logical chunks 18,19 of every row
    if (tid < 128) {
        int r = tid >> 1, c = 18 + (tid & 1);
        short8v z = {0, 0, 0, 0, 0, 0, 0, 0};
        *(short8v*)&A[(r * 40 + (c ^ (r & 7))) * 8] = z;
    }
    __syncthreads();
    // linear float4 staging: block's 64 rows = 9408 consecutive floats (16B-aligned)
    const float4* fb4 = (const float4*)(fb + (long long)row0 * 147);
#pragma unroll 1
    for (int s = 0; s < 5; ++s) {
        int idx = tid + s * 512;
        if (idx < 2352) {
            float4 v = fb4[idx];
            const float* ve = (const float*)&v;
            int k0 = idx * 4;
#pragma unroll
            for (int e = 0; e < 4; ++e) {
                int k = k0 + e;
                int r = k / 147;
                int c = k - r * 147;
                A[(r * 40 + ((c >> 3) ^ (r & 7))) * 8 + (c & 7)] = (short)f2bf(ve[e]);
            }
        }
    }
    __syncthreads();
    const int w = tid >> 6, l = tid & 63;
    const int wr = w >> 2, wc = w & 3;
    const int lr = l & 15, lk = l >> 4, sw = l & 7;
    f32x4 acc[2][5];
#pragma unroll
    for (int ri = 0; ri < 2; ++ri)
#pragma unroll
        for (int i = 0; i < 5; ++i) acc[ri][i] = (f32x4){0.f, 0.f, 0.f, 0.f};
    const short8v* Ald = (const short8v*)A;
#pragma unroll
    for (int ks = 0; ks < 5; ++ks) {
        short8v bfr[2], wv[5];
#pragma unroll
        for (int ri = 0; ri < 2; ++ri)
            bfr[ri] = Ald[((wr * 2 + ri) * 16 + lr) * 40 + ((ks * 4 + lk) ^ sw)];
#pragma unroll
        for (int i = 0; i < 5; ++i)
            wv[i] = *(const short8v*)&Wp[((ks * 20 + wc * 5 + i) * 64 + l) * 8];
#pragma unroll
        for (int ri = 0; ri < 2; ++ri)
#pragma unroll
            for (int i = 0; i < 5; ++i)
                acc[ri][i] = mfma16(wv[i], bfr[ri], acc[ri][i]);
    }
    __syncthreads();
#pragma unroll
    for (int ri = 0; ri < 2; ++ri)
#pragma unroll
        for (int i = 0; i < 5; ++i) {
            const int r = (wr * 2 + ri) * 16 + lr;
            const int c16 = (wc * 5 + i) * 2 + (lk >> 1);
            ushort4 t;
            t.x = f2bf(acc[ri][i][0]); t.y = f2bf(acc[ri][i][1]);
            t.z = f2bf(acc[ri][i][2]); t.w = f2bf(acc[ri][i][3]);
            *(ushort4*)&A[(r * 40 + (c16 ^ (r & 7))) * 8 + (lk & 1) * 4] = t;
        }
    __syncthreads();
    for (int idx = tid; idx < 64 * 38; idx += 512) {
        int r = idx / 38, c = idx - r * 38;
        short8v t = *(const short8v*)&A[(r * 40 + (c ^ (r & 7))) * 8];
        *(short8v*)&inp[(long long)(row0 + r) * 304 + c * 8] = t;
    }
}

// ------ a_msg[a] = sum_nb brelu(msg[a2b[a][nb]])  (bf16, stride 304) ---------
__global__ __launch_bounds__(256) void k_gather(const bfraw* __restrict__ msg,
                                                const int* __restrict__ a2b,
                                                bfraw* __restrict__ amsg) {
    int gid = blockIdx.x * 256 + threadIdx.x;
    if (gid >= 100000 * 19) return;
    int a = gid / 19, c = gid - a * 19;      // handles chunks c and c+19
    const int* nb = a2b + a * 6;
    float s0[8], s1[8];
#pragma unroll
    for (int e = 0; e < 8; ++e) { s0[e] = 0.f; s1[e] = 0.f; }
#pragma unroll
    for (int j = 0; j < 6; ++j) {
        const long long base = (long long)nb[j] * 304;
        const ushort8v v0 = *(const ushort8v*)&msg[base + c * 8];
        const ushort8v v1 = *(const ushort8v*)&msg[base + (c + 19) * 8];
#pragma unroll
        for (int e = 0; e < 8; ++e) {
            s0[e] += bf2f(brelu(v0[e]));
            s1[e] += bf2f(brelu(v1[e]));
        }
    }
    short8v o0, o1;
#pragma unroll
    for (int e = 0; e < 8; ++e) { o0[e] = (short)f2bf(s0[e]); o1[e] = (short)f2bf(s1[e]); }
    *(short8v*)&amsg[(long long)a * 304 + c * 8] = o0;
    *(short8v*)&amsg[(long long)a * 304 + (c + 19) * 8] = o1;
}

// --- out = inp + (amsg[b2a] - brelu(msg[b2revb])) @ W_h  (bf16 pre-relu) -----
__global__ __launch_bounds__(512, 4) void k_bond(const bfraw* __restrict__ amsg,
                                                 const bfraw* __restrict__ msg,
                                                 const bfraw* __restrict__ inp,
                                                 const int* __restrict__ b2a,
                                                 const int* __restrict__ b2revb,
                                                 const bfraw* __restrict__ Wp,
                                                 bfraw* __restrict__ out) {
    __shared__ short A[64 * 40 * 8];   // 40960 B
    const int row0 = blockIdx.x * 64;
    const int tid = threadIdx.x;
    // zero the K-pad region: logical chunks 38,39
    if (tid < 128) {
        int r = tid >> 1, c = 38 + (tid & 1);
        short8v z = {0, 0, 0, 0, 0, 0, 0, 0};
        *(short8v*)&A[(r * 40 + (c ^ (r & 7))) * 8] = z;
    }
    // ---- staging: preload indices, then issue ALL scattered loads (10 deep) ----
    int rr[5], cc[5], ia[5], irv[5];
#pragma unroll
    for (int s = 0; s < 5; ++s) {
        int idx = tid + s * 512;
        if (s < 4 || idx < 2432) {
            rr[s] = idx / 38; cc[s] = idx - rr[s] * 38;
            const int b = row0 + rr[s];
            ia[s] = b2a[b];
            irv[s] = b2revb[b];
        }
    }
    ushort8v va[5], vm[5];
#pragma unroll
    for (int s = 0; s < 5; ++s) {
        int idx = tid + s * 512;
        if (s < 4 || idx < 2432) {
            va[s] = *(const ushort8v*)&amsg[(long long)ia[s] * 304 + cc[s] * 8];
            vm[s] = *(const ushort8v*)&msg[(long long)irv[s] * 304 + cc[s] * 8];
        }
    }
#pragma unroll
    for (int s = 0; s < 5; ++s) {
        int idx = tid + s * 512;
        if (s < 4 || idx < 2432) {
            short8v pk;
#pragma unroll
            for (int j = 0; j < 8; ++j)
                pk[j] = (short)f2bf(bf2f(va[s][j]) - bf2f(brelu(vm[s][j])));
            *(short8v*)&A[(rr[s] * 40 + (cc[s] ^ (rr[s] & 7))) * 8] = pk;
        }
    }
    __syncthreads();
    const int w = tid >> 6, l = tid & 63;
    const int wr = w >> 2, wc = w & 3;
    const int lr = l & 15, lk = l >> 4, sw = l & 7;
    f32x4 acc[2][5];
#pragma unroll
    for (int ri = 0; ri < 2; ++ri)
#pragma unroll
        for (int i = 0; i < 5; ++i) acc[ri][i] = (f32x4){0.f, 0.f, 0.f, 0.f};
    const short8v* Ald = (const short8v*)A;
#pragma unroll
    for (int ks = 0; ks < 10; ++ks) {
        short8v bfr[2], wv[5];
#pragma unroll
        for (int ri = 0; ri < 2; ++ri)
            bfr[ri] = Ald[((wr * 2 + ri) * 16 + lr) * 40 + ((ks * 4 + lk) ^ sw)];
#pragma unroll
        for (int i = 0; i < 5; ++i)
            wv[i] = *(const short8v*)&Wp[((ks * 20 + wc * 5 + i) * 64 + l) * 8];
#pragma unroll
        for (int ri = 0; ri < 2; ++ri)
#pragma unroll
            for (int i = 0; i < 5; ++i)
                acc[ri][i] = mfma16(wv[i], bfr[ri], acc[ri][i]);
    }
    __syncthreads();
#pragma unroll
    for (int ri = 0; ri < 2; ++ri)
#pragma unroll
        for (int i = 0; i < 5; ++i) {
            const int r = (wr * 2 + ri) * 16 + lr;
            const int c16 = (wc * 5 + i) * 2 + (lk >> 1);
            ushort4 t;
            t.x = f2bf(acc[ri][i][0]); t.y = f2bf(acc[ri][i][1]);
            t.z = f2bf(acc[ri][i][2]); t.w = f2bf(acc[ri][i][3]);
            *(ushort4*)&A[(r * 40 + (c16 ^ (r & 7))) * 8 + (lk & 1) * 4] = t;
        }
    __syncthreads();
    // epilogue: batch the linear inp loads, then combine + store
    ushort8v ip[5];
#pragma unroll
    for (int s = 0; s < 5; ++s) {
        int idx = tid + s * 512;
        if (s < 4 || idx < 2432) {
            int r = idx / 38, c = idx - r * 38;
            ip[s] = *(const ushort8v*)&inp[(long long)(row0 + r) * 304 + c * 8];
        }
    }
#pragma unroll
    for (int s = 0; s < 5; ++s) {
        int idx = tid + s * 512;
        if (s < 4 || idx < 2432) {
            int r = idx / 38, c = idx - r * 38;
            short8v t = *(const short8v*)&A[(r * 40 + (c ^ (r & 7))) * 8];
            short8v m;
#pragma unroll
            for (int j = 0; j < 8; ++j)
                m[j] = (short)f2bf(bf2f(ip[s][j]) + bf2f((unsigned short)t[j]));
            *(short8v*)&out[(long long)(row0 + r) * 304 + c * 8] = m;
        }
    }
}

// --- hid = relu(f_atoms @ Wo_fa + (gather msg) @ Wo_am + b_o) (bf16) ---------
// Gather #3 fused into phase-1 staging (pair-batched: 12 loads in flight).
__global__ __launch_bounds__(512, 4) void k_out(const float* __restrict__ fa,
                                                const bfraw* __restrict__ msg,
                                                const int* __restrict__ a2b,
                                                const bfraw* __restrict__ WfP,
                                                const bfraw* __restrict__ WaP,
                                                const float* __restrict__ bo,
                                                bfraw* __restrict__ hid) {
    __shared__ short A[64 * 40 * 8];
    const int row0 = blockIdx.x * 64;
    const int tid = threadIdx.x;
    const int nvalid = (row0 + 64 <= 100000) ? 64 : (100000 - row0);
    // phase 1 staging: amsg row = sum_j brelu(msg[a2b[row][j]]); 2-unit batches
#pragma unroll 1
    for (int sp = 0; sp < 5; sp += 2) {
        ushort8v v[2][6];
        int ur[2], uc[2], act[2];
#pragma unroll
        for (int u = 0; u < 2; ++u) {
            act[u] = 0;
            int s = sp + u;
            if (s < 5) {
                int idx = tid + s * 512;
                int r = idx / 40, c = idx - r * 40;
                ur[u] = r; uc[u] = c;
                const int row = row0 + r;
                if (c < 38 && row < 100000) {
                    act[u] = 1;
                    const int* nb = a2b + row * 6;
#pragma unroll
                    for (int j = 0; j < 6; ++j)
                        v[u][j] = *(const ushort8v*)&msg[(long long)nb[j] * 304 + c * 8];
                }
            }
        }
#pragma unroll
        for (int u = 0; u < 2; ++u) {
            int s = sp + u;
            if (s >= 5) continue;
            short8v pk;
            if (act[u]) {
                float sm[8];
#pragma unroll
                for (int e = 0; e < 8; ++e) sm[e] = 0.f;
#pragma unroll
                for (int j = 0; j < 6; ++j)
#pragma unroll
                    for (int e = 0; e < 8; ++e) sm[e] += bf2f(brelu(v[u][j][e]));
#pragma unroll
                for (int e = 0; e < 8; ++e) pk[e] = (short)f2bf(sm[e]);
            } else {
#pragma unroll
                for (int e = 0; e < 8; ++e) pk[e] = 0;
            }
            *(short8v*)&A[(ur[u] * 40 + (uc[u] ^ (ur[u] & 7))) * 8] = pk;
        }
    }
    __syncthreads();
    const int w = tid >> 6, l = tid & 63;
    const int wr = w >> 2, wc = w & 3;
    const int lr = l & 15, lk = l >> 4, sw = l & 7;
    f32x4 acc[2][5];
#pragma unroll
    for (int ri = 0; ri < 2; ++ri)
#pragma unroll
        for (int i = 0; i < 5; ++i) acc[ri][i] = (f32x4){0.f, 0.f, 0.f, 0.f};
    const short8v* Ald = (const short8v*)A;
#pragma unroll
    for (int ks = 0; ks < 10; ++ks) {
        short8v bfr[2], wv[5];
#pragma unroll
        for (int ri = 0; ri < 2; ++ri)
            bfr[ri] = Ald[((wr * 2 + ri) * 16 + lr) * 40 + ((ks * 4 + lk) ^ sw)];
#pragma unroll
        for (int i = 0; i < 5; ++i)
            wv[i] = *(const short8v*)&WaP[((ks * 20 + wc * 5 + i) * 64 + l) * 8];
#pragma unroll
        for (int ri = 0; ri < 2; ++ri)
#pragma unroll
            for (int i = 0; i < 5; ++i)
                acc[ri][i] = mfma16(wv[i], bfr[ri], acc[ri][i]);
    }
    __syncthreads();
    // phase 2: f_atoms @ Wo_fa (accumulate). Zero K-pad chunks 16..19 first.
    if (tid < 256) {
        int r = tid >> 2, c = 16 + (tid & 3);
        short8v z = {0, 0, 0, 0, 0, 0, 0, 0};
        *(short8v*)&A[(r * 40 + (c ^ (r & 7))) * 8] = z;
    }
    __syncthreads();
    // linear float4 staging of f_atoms
    {
        const float4* fa4 = (const float4*)(fa + (long long)row0 * 133);
        const int limit4 = (nvalid * 133) >> 2;
#pragma unroll 1
        for (int s = 0; s < 5; ++s) {
            int idx = tid + s * 512;
            if (idx < limit4) {
                float4 v = fa4[idx];
                const float* ve = (const float*)&v;
                int k0 = idx * 4;
#pragma unroll
                for (int e = 0; e < 4; ++e) {
                    int k = k0 + e;
                    int r = k / 133;
                    int c = k - r * 133;
                    A[(r * 40 + ((c >> 3) ^ (r & 7))) * 8 + (c & 7)] = (short)f2bf(ve[e]);
                }
            }
        }
    }
    __syncthreads();
#pragma unroll
    for (int ks = 0; ks < 5; ++ks) {
        short8v bfr[2], wv[5];
#pragma unroll
        for (int ri = 0; ri < 2; ++ri)
            bfr[ri] = Ald[((wr * 2 + ri) * 16 + lr) * 40 + ((ks * 4 + lk) ^ sw)];
#pragma unroll
        for (int i = 0; i < 5; ++i)
            wv[i] = *(const short8v*)&WfP[((ks * 20 + wc * 5 + i) * 64 + l) * 8];
#pragma unroll
        for (int ri = 0; ri < 2; ++ri)
#pragma unroll
            for (int i = 0; i < 5; ++i)
                acc[ri][i] = mfma16(wv[i], bfr[ri], acc[ri][i]);
    }
    __syncthreads();
#pragma unroll
    for (int ri = 0; ri < 2; ++ri)
#pragma unroll
        for (int i = 0; i < 5; ++i) {
            const int r = (wr * 2 + ri) * 16 + lr;
            const int c16 = (wc * 5 + i) * 2 + (lk >> 1);
            ushort4 t;
            t.x = f2bf(acc[ri][i][0]); t.y = f2bf(acc[ri][i][1]);
            t.z = f2bf(acc[ri][i][2]); t.w = f2bf(acc[ri][i][3]);
            *(ushort4*)&A[(r * 40 + (c16 ^ (r & 7))) * 8 + (lk & 1) * 4] = t;
        }
    __syncthreads();
    for (int idx = tid; idx < 64 * 38; idx += 512) {
        int r = idx / 38, c = idx - r * 38;
        const int row = row0 + r;
        if (row >= 100000) continue;
        short8v t = *(const short8v*)&A[(r * 40 + (c ^ (r & 7))) * 8];
        float4 b0 = *(const float4*)&bo[c * 8];
        float4 b1 = (c < 37) ? *(const float4*)&bo[c * 8 + 4]
                             : make_float4(0.f, 0.f, 0.f, 0.f);
        float bias[8] = {b0.x, b0.y, b0.z, b0.w, b1.x, b1.y, b1.z, b1.w};
        short8v m;
#pragma unroll
        for (int j = 0; j < 8; ++j)
            m[j] = (short)f2bf(fmaxf(bf2f((unsigned short)t[j]) + bias[j], 0.f));
        *(short8v*)&hid[(long long)row * 304 + c * 8] = m;
    }
}

// ------- out[m] = mean of hid rows with mol_ids == m (0 if none) -------------
// Coalesced: thread (p, c) sums chunk c over rows start+p, start+p+8, ...
__global__ __launch_bounds__(320) void k_mean(const bfraw* __restrict__ hid,
                                              const int* __restrict__ mol,
                                              float* __restrict__ out) {
    __shared__ float red[8][304];
    const int m = blockIdx.x;
    const int natoms = 100000;
    int lo = 0, hi = natoms;
    while (lo < hi) { int mid = (lo + hi) >> 1; if (mol[mid] < m) lo = mid + 1; else hi = mid; }
    const int start = lo;
    lo = start; hi = natoms;
    while (lo < hi) { int mid = (lo + hi) >> 1; if (mol[mid] <= m) lo = mid + 1; else hi = mid; }
    const int end = lo;
    const int tid = threadIdx.x;
    const int p = tid / 38, c = tid - p * 38;   // valid for tid < 304
    if (tid < 304) {
        float s[8];
#pragma unroll
        for (int e = 0; e < 8; ++e) s[e] = 0.f;
        for (int a = start + p; a < end; a += 8) {
            const ushort8v v = *(const ushort8v*)&hid[(long long)a * 304 + c * 8];
#pragma unroll
            for (int e = 0; e < 8; ++e) s[e] += bf2f(v[e]);
        }
#pragma unroll
        for (int e = 0; e < 8; ++e) red[p][c * 8 + e] = s[e];
    }
    __syncthreads();
    if (tid < 300) {
        float t = 0.f;
#pragma unroll
        for (int p2 = 0; p2 < 8; ++p2) t += red[p2][tid];
        const int n = end - start;
        out[m * 300 + tid] = (n > 0) ? (t / (float)n) : 0.f;
    }
}

extern "C" void kernel_launch(void* const* d_in, const int* in_sizes, int n_in,
                              void* d_out, int out_size, void* d_ws, size_t ws_size,
                              hipStream_t stream) {
    const float* f_atoms = (const float*)d_in[0];
    const float* f_bonds = (const float*)d_in[1];
    const int* a2b      = (const int*)d_in[2];
    const int* b2a      = (const int*)d_in[3];
    const int* b2revb   = (const int*)d_in[4];
    const int* mol_ids  = (const int*)d_in[5];
    const float* W_i    = (const float*)d_in[6];
    const float* W_h    = (const float*)d_in[7];
    const float* W_o    = (const float*)d_in[8];
    const float* b_o    = (const float*)d_in[9];
    float* out = (float*)d_out;

    // ws layout (bytes): bf16 rows at stride 304 (608 B); msgs PRE-relu
    //   inp  @ 0            121,600,000
    //   M1   @ 121,600,000  121,600,000  (bond1 out; reused as hid)
    //   M2   @ 243,200,000  121,600,000  (bond2 out)
    //   amsg @ 364,800,000   60,800,000
    //   packed weights @ 425,600,000
    char* wsb = (char*)d_ws;
    bfraw* inp  = (bfraw*)(wsb);
    bfraw* M1   = (bfraw*)(wsb + 121600000ll);
    bfraw* M2   = (bfraw*)(wsb + 243200000ll);
    bfraw* amsg = (bfraw*)(wsb + 364800000ll);
    bfraw* WiP   = (bfraw*)(wsb + 425600000ll);
    bfraw* WhP   = (bfraw*)(wsb + 425702400ll);
    bfraw* WoFaP = (bfraw*)(wsb + 425907200ll);
    bfraw* WoAmP = (bfraw*)(wsb + 426009600ll);

    k_pack<<<100, 64, 0, stream>>>(W_i, 147, 0, WiP);
    k_pack<<<200, 64, 0, stream>>>(W_h, 300, 0, WhP);
    k_pack<<<100, 64, 0, stream>>>(W_o, 133, 0, WoFaP);
    k_pack<<<200, 64, 0, stream>>>(W_o, 300, 133, WoAmP);

    const int nb_blocks = 200000 / 64;          // 3125
    const int na_blocks = (100000 + 63) / 64;   // 1563
    const int gather_blocks = (100000 * 19 + 255) / 256;

    k_in<<<nb_blocks, 512, 0, stream>>>(f_bonds, WiP, inp);

    k_gather<<<gather_blocks, 256, 0, stream>>>(inp, a2b, amsg);
    k_bond<<<nb_blocks, 512, 0, stream>>>(amsg, inp, inp, b2a, b2revb, WhP, M1);
    k_gather<<<gather_blocks, 256, 0, stream>>>(M1, a2b, amsg);
    k_bond<<<nb_blocks, 512, 0, stream>>>(amsg, M1, inp, b2a, b2revb, WhP, M2);

    bfraw* hid = M1;   // M1 dead after bond2
    k_out<<<na_blocks, 512, 0, stream>>>(f_atoms, M2, a2b, WoFaP, WoAmP, b_o, hid);
    k_mean<<<4000, 320, 0, stream>>>(hid, mol_ids, out);
}